// Round 4
// baseline (629.207 us; speedup 1.0000x reference)
//
#include <hip/hip_runtime.h>
#include <stdint.h>
#include <stddef.h>

typedef __attribute__((ext_vector_type(8))) short short8;
typedef __attribute__((ext_vector_type(16))) float f32x16;

#define CI 128
#define CO 128
#define SP 32768          // 32*32*32
#define BATCH 8
#define STYLED 512
#define KV 3456           // CI*27

#define WGR 6912          // weight 16B-granules per ci16-chunk: 27*128*32B/16
#define XGR 2448          // x granules per chunk: 1224 rows * 2
#define WCHUNK_BYTES (WGR * 16)   // 110592

typedef __attribute__((address_space(1))) const void gvoid_t;
typedef __attribute__((address_space(3))) void lvoid_t;
__device__ __forceinline__ void gload16(const void* g, void* l) {
    __builtin_amdgcn_global_load_lds((gvoid_t*)g, (lvoid_t*)l, 16, 0, 0);
}

__device__ __forceinline__ short f2bf(float f) {
    uint32_t u = __builtin_bit_cast(uint32_t, f);
    u = (u + 0x7FFFu + ((u >> 16) & 1u)) >> 16;
    return (short)(u & 0xFFFFu);
}

// style_m[b][i] = 1 + affine_b[i] + sum_d s[b][d]*affine_w[i][d]; block 0 zeros zp
__global__ void k_style(const float* __restrict__ s, const float* __restrict__ aw,
                        const float* __restrict__ ab, float* __restrict__ m,
                        float* __restrict__ zp) {
    __shared__ float ssh[STYLED];
    int b = blockIdx.x;
    int i = threadIdx.x;  // 128 threads
    if (b == 0 && i < 64) zp[i] = 0.f;   // 256B zeropage
    for (int r = 0; r < STYLED / 128; ++r) ssh[r * 128 + i] = s[b * STYLED + r * 128 + i];
    __syncthreads();
    float acc = ab[i] + 1.0f;
    const float4* awr = (const float4*)(aw + (size_t)i * STYLED);
    for (int d4 = 0; d4 < STYLED / 4; ++d4) {
        float4 v = awr[d4];
        acc += v.x * ssh[d4 * 4] + v.y * ssh[d4 * 4 + 1] + v.z * ssh[d4 * 4 + 2] + v.w * ssh[d4 * 4 + 3];
    }
    m[b * CI + i] = acc;
}

// wmodT layout [b][c16][tap][o][16ci] — linear match for LDS staging
__global__ void k_wmod(const float* __restrict__ w, const float* __restrict__ m,
                       short* __restrict__ wt) {
    int b = blockIdx.x >> 7;
    int o = blockIdx.x & 127;
    int lane = threadIdx.x;   // 64 threads
    const float* wrow = w + (size_t)o * KV;
    const float* mrow = m + b * CI;
    float sum = 0.f;
    for (int e = lane; e < KV; e += 64) {
        int i = e / 27;
        float v = wrow[e] * mrow[i];
        sum += v * v;
    }
    #pragma unroll
    for (int off = 32; off >= 1; off >>= 1) sum += __shfl_xor(sum, off);
    float scale = 1.0f / sqrtf(sum + 1e-8f);
    for (int e = lane; e < KV; e += 64) {
        int i = e / 27;
        int k = e - i * 27;
        float v = wrow[e] * mrow[i] * scale;
        int c = i >> 4, cl = i & 15;
        wt[(((size_t)(b * 8 + c) * 27 + k) * 128 + o) * 16 + cl] = f2bf(v);
    }
}

// xT[b][sp][ci] bf16 from x[b][ci][z][y][w] f32. Thread = 1 sp, 32 ch.
__global__ void k_xt(const float* __restrict__ x, short* __restrict__ xt) {
    int bid = blockIdx.x;              // 4096 = 8b * 4c * 128spb
    int b = bid >> 9, c = (bid >> 7) & 3, spb = bid & 127;
    int sp = spb * 256 + threadIdx.x;
    const float* src = x + ((size_t)(b * CI + c * 32)) * SP + sp;
    float f[32];
    #pragma unroll
    for (int ch = 0; ch < 32; ++ch) f[ch] = src[(size_t)ch * SP];
    short8 v[4];
    #pragma unroll
    for (int q = 0; q < 4; ++q)
        #pragma unroll
        for (int j = 0; j < 8; ++j) v[q][j] = f2bf(f[q * 8 + j]);
    short* dst = xt + (size_t)(b * SP + sp) * CI + c * 32;
    #pragma unroll
    for (int q = 0; q < 4; ++q) *(short8*)(dst + q * 8) = v[q];
}

// Implicit-GEMM conv. Block = 128co x 512sp (4z*4y*32w), 8 waves of 64x128,
// mfma_f32_32x32x16_bf16, ci-chunks of 16. Whole 27-tap pass per chunk with
// only 3 barriers: reg-prefetched w[taps0..13]+x staged by ds_write, w[14..26]
// via global_load_lds landing under taps0..13's MFMA.
__launch_bounds__(512, 2)
__global__ void k_conv(const short* __restrict__ xt, const short* __restrict__ wt,
                       const float* __restrict__ bias, float* __restrict__ out,
                       const short* __restrict__ zp) {
    __shared__ short lds[(WGR + XGR) * 8];   // 149,760 B

    int bid = blockIdx.x;
    int b = bid & 7;                  // sample -> XCD affinity (weights L2-resident)
    int s = bid >> 3;                 // 0..63
    int z0 = (s & 7) * 4, y0 = (s >> 3) * 4;
    int tid = threadIdx.x, lane = tid & 63, wid = tid >> 6;
    int wm = wid >> 2;                // co half
    int wn = wid & 3;                 // z within tile
    int l31 = lane & 31, g = lane >> 5;

    const char* xb = (const char*)(xt + (size_t)b * SP * CI);
    const char* wb = (const char*)wt + (size_t)b * 8 * WCHUNK_BYTES;

    // chunk-invariant x-granule source byte offsets (-1 = OOB -> zeropage)
    int xoff[5];
    #pragma unroll
    for (int j = 0; j < 5; ++j) {
        int gx = tid + 512 * j;
        int row = gx >> 1, half = gx & 1;
        int zh = row / 204, r2 = row - zh * 204;
        int yh = r2 / 34, wh = r2 - yh * 34;
        int zz = z0 + zh - 1, yy = y0 + yh - 1, ww = wh - 1;
        bool ok = (gx < XGR) && ((unsigned)zz < 32u) && ((unsigned)yy < 32u) && ((unsigned)ww < 32u);
        xoff[j] = ok ? ((zz * 1024 + yy * 32 + ww) * CI * 2 + half * 16) : -1;
    }

    f32x16 acc[2][4];
    #pragma unroll
    for (int mf = 0; mf < 2; ++mf)
        #pragma unroll
        for (int nf = 0; nf < 4; ++nf)
            #pragma unroll
            for (int e = 0; e < 16; ++e) acc[mf][nf][e] = 0.f;

    // prologue: prefetch chunk 0 into regs
    short8 wreg[7], xreg[5];
    #pragma unroll
    for (int k = 0; k < 7; ++k)
        wreg[k] = *(const short8*)(wb + (tid + 512 * k) * 16);
    #pragma unroll
    for (int j = 0; j < 5; ++j)
        if (tid + 512 * j < XGR) {
            const char* src = (xoff[j] >= 0) ? (xb + xoff[j]) : (const char*)zp;
            xreg[j] = *(const short8*)src;
        }

    #pragma unroll 1
    for (int c = 0; c < 8; ++c) {
        __syncthreads();                       // prior chunk fully consumed
        #pragma unroll
        for (int k = 0; k < 7; ++k)
            *(short8*)&lds[(tid + 512 * k) * 8] = wreg[k];
        #pragma unroll
        for (int j = 0; j < 5; ++j)
            if (tid + 512 * j < XGR)
                *(short8*)&lds[(WGR + tid + 512 * j) * 8] = xreg[j];
        __syncthreads();                       // stage visible

        const char* wbc = wb + (size_t)c * WCHUNK_BYTES;
        // async: stage this chunk's taps 14..26 (granules 3584..6911)
        #pragma unroll
        for (int j2 = 0; j2 < 7; ++j2) {
            int i = wid + 8 * j2;
            if (i < 52)
                gload16(wbc + (3584 + i * 64 + lane) * 16,
                        (void*)((char*)lds + (3584 + i * 64) * 16));
        }
        // prefetch chunk c+1 into regs (hidden under taps)
        if (c < 7) {
            const char* wbn = wbc + WCHUNK_BYTES;
            #pragma unroll
            for (int k = 0; k < 7; ++k)
                wreg[k] = *(const short8*)(wbn + (tid + 512 * k) * 16);
            #pragma unroll
            for (int j = 0; j < 5; ++j)
                if (tid + 512 * j < XGR) {
                    const char* src = (xoff[j] >= 0) ? (xb + xoff[j] + (c + 1) * 32)
                                                     : (const char*)zp;
                    xreg[j] = *(const short8*)src;
                }
        }

        // taps 0..13 (barrier-free)
        #pragma unroll
        for (int tap = 0; tap < 14; ++tap) {
            int kd = tap / 9, r9 = tap - kd * 9;
            int kh = r9 / 3, kw = r9 - kh * 3;
            short8 af[2];
            #pragma unroll
            for (int mf = 0; mf < 2; ++mf)
                af[mf] = *(const short8*)&lds[(tap * 128 + wm * 64 + mf * 32 + l31) * 16 + g * 8];
            #pragma unroll
            for (int nf = 0; nf < 4; ++nf) {
                int row = (wn + kd) * 204 + (nf + kh) * 34 + l31 + kw;
                short8 bf = *(const short8*)&lds[WGR * 8 + row * 16 + g * 8];
                acc[0][nf] = __builtin_amdgcn_mfma_f32_32x32x16_bf16(af[0], bf, acc[0][nf], 0, 0, 0);
                acc[1][nf] = __builtin_amdgcn_mfma_f32_32x32x16_bf16(af[1], bf, acc[1][nf], 0, 0, 0);
            }
        }

        __syncthreads();                       // drains vmcnt: taps14..26 landed

        // taps 14..26 (barrier-free; c+1 prefetch still in flight ok)
        #pragma unroll
        for (int tap = 14; tap < 27; ++tap) {
            int kd = tap / 9, r9 = tap - kd * 9;
            int kh = r9 / 3, kw = r9 - kh * 3;
            short8 af[2];
            #pragma unroll
            for (int mf = 0; mf < 2; ++mf)
                af[mf] = *(const short8*)&lds[(tap * 128 + wm * 64 + mf * 32 + l31) * 16 + g * 8];
            #pragma unroll
            for (int nf = 0; nf < 4; ++nf) {
                int row = (wn + kd) * 204 + (nf + kh) * 34 + l31 + kw;
                short8 bf = *(const short8*)&lds[WGR * 8 + row * 16 + g * 8];
                acc[0][nf] = __builtin_amdgcn_mfma_f32_32x32x16_bf16(af[0], bf, acc[0][nf], 0, 0, 0);
                acc[1][nf] = __builtin_amdgcn_mfma_f32_32x32x16_bf16(af[1], bf, acc[1][nf], 0, 0, 0);
            }
        }
    }

    // epilogue: D col=lane&31 (sp-w), row=(reg&3)+8*(reg>>2)+4*(lane>>5) (co)
    size_t ob = (size_t)b * CO * SP;
    #pragma unroll
    for (int mf = 0; mf < 2; ++mf)
        #pragma unroll
        for (int nf = 0; nf < 4; ++nf) {
            int z = z0 + wn, y = y0 + nf;
            size_t base = ob + (size_t)z * 1024 + y * 32 + l31;
            #pragma unroll
            for (int j = 0; j < 16; ++j) {
                int co = wm * 64 + mf * 32 + (j & 3) + 8 * (j >> 2) + 4 * g;
                out[base + (size_t)co * SP] = acc[mf][nf][j] + bias[co];
            }
        }
}

extern "C" void kernel_launch(void* const* d_in, const int* in_sizes, int n_in,
                              void* d_out, int out_size, void* d_ws, size_t ws_size,
                              hipStream_t stream) {
    const float* x  = (const float*)d_in[0];
    const float* s  = (const float*)d_in[1];
    const float* w  = (const float*)d_in[2];
    const float* bb = (const float*)d_in[3];
    const float* aw = (const float*)d_in[4];
    const float* ab = (const float*)d_in[5];
    float* out = (float*)d_out;

    // workspace layout
    float* style_m = (float*)d_ws;                                      // 4 KB
    short* wmodT   = (short*)((char*)d_ws + 4096);                      // 7,077,888 B
    short* xT      = (short*)((char*)d_ws + 4096 + 7077888);            // 67,108,864 B
    float* zpage   = (float*)((char*)d_ws + 4096 + 7077888 + 67108864); // 256 B zeros

    k_style<<<BATCH, 128, 0, stream>>>(s, aw, ab, style_m, zpage);
    k_wmod<<<BATCH * CO, 64, 0, stream>>>(w, style_m, wmodT);
    k_xt<<<BATCH * 4 * 128, 256, 0, stream>>>(x, xT);
    k_conv<<<BATCH * 64, 512, 0, stream>>>(xT, wmodT, bb, out, (const short*)zpage);
}

// Round 5
// 489.263 us; speedup vs baseline: 1.2860x; 1.2860x over previous
//
#include <hip/hip_runtime.h>
#include <stdint.h>
#include <stddef.h>

typedef __attribute__((ext_vector_type(8))) short short8;
typedef __attribute__((ext_vector_type(4))) float floatx4;

#define CI 128
#define CO 128
#define SP 32768          // 32*32*32
#define BATCH 8
#define STYLED 512
#define KV 3456           // CI*27

typedef __attribute__((address_space(1))) const void gvoid_t;
typedef __attribute__((address_space(3))) void lvoid_t;
__device__ __forceinline__ void gload16(const void* g, void* l) {
    __builtin_amdgcn_global_load_lds((gvoid_t*)g, (lvoid_t*)l, 16, 0, 0);
}

__device__ __forceinline__ short f2bf(float f) {
    uint32_t u = __builtin_bit_cast(uint32_t, f);
    u = (u + 0x7FFFu + ((u >> 16) & 1u)) >> 16;
    return (short)(u & 0xFFFFu);
}

// style_m[b][i] = 1 + affine_b[i] + sum_d s[b][d]*affine_w[i][d]; block 0 zeros zp
__global__ void k_style(const float* __restrict__ s, const float* __restrict__ aw,
                        const float* __restrict__ ab, float* __restrict__ m,
                        float* __restrict__ zp) {
    __shared__ float ssh[STYLED];
    int b = blockIdx.x;
    int i = threadIdx.x;  // 128 threads
    if (b == 0 && i < 64) zp[i] = 0.f;   // 256B zeropage
    for (int r = 0; r < STYLED / 128; ++r) ssh[r * 128 + i] = s[b * STYLED + r * 128 + i];
    __syncthreads();
    float acc = ab[i] + 1.0f;
    const float4* awr = (const float4*)(aw + (size_t)i * STYLED);
    for (int d4 = 0; d4 < STYLED / 4; ++d4) {
        float4 v = awr[d4];
        acc += v.x * ssh[d4 * 4] + v.y * ssh[d4 * 4 + 1] + v.z * ssh[d4 * 4 + 2] + v.w * ssh[d4 * 4 + 3];
    }
    m[b * CI + i] = acc;
}

// wmodT[b][c32][tap][o][32] pre-swizzled: logical (o, granule g) stored at g ^ ((o>>1)&3)
__global__ void k_wmod(const float* __restrict__ w, const float* __restrict__ m,
                       short* __restrict__ wt) {
    int b = blockIdx.x >> 7;
    int o = blockIdx.x & 127;
    int lane = threadIdx.x;   // 64 threads
    const float* wrow = w + (size_t)o * KV;
    const float* mrow = m + b * CI;
    float sum = 0.f;
    for (int e = lane; e < KV; e += 64) {
        int i = e / 27;
        float v = wrow[e] * mrow[i];
        sum += v * v;
    }
    #pragma unroll
    for (int off = 32; off >= 1; off >>= 1) sum += __shfl_xor(sum, off);
    float scale = 1.0f / sqrtf(sum + 1e-8f);
    int ophase = (o >> 1) & 3;
    for (int e = lane; e < KV; e += 64) {
        int i = e / 27;
        int k = e - i * 27;
        float v = wrow[e] * mrow[i] * scale;
        int c = i >> 5, il = i & 31, g = il >> 3, r = il & 7;
        int gl = g ^ ophase;
        wt[(((size_t)((b * 4 + c) * 27 + k)) * 128 + o) * 32 + gl * 8 + r] = f2bf(v);
    }
}

// xT[b][sp][ci] bf16 from x[b][ci][z][y][w] f32. Thread = 1 sp, 32 ch.
__global__ void k_xt(const float* __restrict__ x, short* __restrict__ xt) {
    int bid = blockIdx.x;              // 4096 = 8b * 4c * 128spb
    int b = bid >> 9, c = (bid >> 7) & 3, spb = bid & 127;
    int sp = spb * 256 + threadIdx.x;
    const float* src = x + ((size_t)(b * CI + c * 32)) * SP + sp;
    float f[32];
    #pragma unroll
    for (int ch = 0; ch < 32; ++ch) f[ch] = src[(size_t)ch * SP];
    short8 v[4];
    #pragma unroll
    for (int q = 0; q < 4; ++q)
        #pragma unroll
        for (int j = 0; j < 8; ++j) v[q][j] = f2bf(f[q * 8 + j]);
    short* dst = xt + (size_t)(b * SP + sp) * CI + c * 32;
    #pragma unroll
    for (int q = 0; q < 4; ++q) *(short8*)(dst + q * 8) = v[q];
}

// Implicit-GEMM conv, R2 data plan + register-pipelined tap schedule.
// Block = (b, ztile(2), ytile(4)); M=128 c_out, N=256 spatial; 8 waves 2Mx4N,
// wave tile 64x64, 16x16x32 MFMA. Weights triple-buffered (gload_lds, vmcnt(1)).
// Per tap: bf(t) read BEFORE barrier (x stable), af(t+1) read after barrier into
// alternate reg set; MFMA(t) consumes regs loaded one tap earlier.
__launch_bounds__(512, 4)
__global__ void k_conv(const short* __restrict__ xt, const short* __restrict__ wt,
                       const float* __restrict__ bias, float* __restrict__ out,
                       const short* __restrict__ zp) {
    __shared__ short lds_x[816 * 32];     // 52224 B, linear rows of 64B
    __shared__ short lds_w0[128 * 32];    // 3 x 8192 B weight buffers
    __shared__ short lds_w1[128 * 32];
    __shared__ short lds_w2[128 * 32];

    int bid = blockIdx.x;
    int b = bid & 7;                 // sample -> XCD affinity (weights L2-resident)
    int t0 = bid >> 3;               // 0..127
    int zt = t0 & 15, yt = t0 >> 4;
    int z0 = zt * 2, y0 = yt * 4;

    int tid = threadIdx.x;
    int lane = tid & 63;
    int wid = tid >> 6;
    int wm = wid >> 2;               // 0..1 : o-tile base wm*64
    int wn = wid & 3;                // 0..3 : spatial tile base wn*64
    int l15 = lane & 15;
    int lhi = lane >> 4;

    floatx4 acc[4][4];
    #pragma unroll
    for (int a = 0; a < 4; ++a)
        #pragma unroll
        for (int c = 0; c < 4; ++c) acc[a][c] = (floatx4){0.f, 0.f, 0.f, 0.f};

    const short* wb = wt + (size_t)b * (4 * 27 * 128 * 32);
    const short* xb = xt + (size_t)b * SP * CI;

    short* const wbuf[3] = {lds_w0, lds_w1, lds_w2};

    #pragma unroll 1
    for (int c = 0; c < 4; ++c) {    // c_in chunks of 32
        __syncthreads();             // prior chunk's LDS reads fully retired
        // ---- stage x halo chunk: 816 rows * 4 granules = 51 wave-issues ----
        for (int j = 0; ; ++j) {
            int s = wid + 8 * j;
            if (s >= 51) break;
            int G = s * 64 + lane;
            int rowid = G >> 2, g = G & 3;
            int zh = rowid / 204; int rr = rowid - zh * 204;
            int yh = rr / 34;     int wh = rr - yh * 34;
            int zz = z0 + zh - 1, yy = y0 + yh - 1, ww = wh - 1;
            int q = g ^ ((rowid >> 1) & 3);          // source pre-swizzle
            const short* src;
            if ((unsigned)zz < 32u && (unsigned)yy < 32u && (unsigned)ww < 32u)
                src = xb + ((size_t)(zz * 1024 + yy * 32 + ww)) * CI + c * 32 + q * 8;
            else
                src = zp + q * 8;
            gload16(src, (void*)((char*)lds_x + s * 1024));
        }
        const short* wbc = wb + (size_t)c * 27 * 4096;
        gload16(wbc + (size_t)0 * 4096 + wid * 512 + lane * 8,
                (void*)((char*)lds_w0 + wid * 1024));
        gload16(wbc + (size_t)1 * 4096 + wid * 512 + lane * 8,
                (void*)((char*)lds_w1 + wid * 1024));
        asm volatile("s_waitcnt vmcnt(1)" ::: "memory");   // x + tap0 landed
        __builtin_amdgcn_s_barrier();
        asm volatile("" ::: "memory");

        // prologue: af(0) -> set A
        short8 afA[4], afB[4];
        #pragma unroll
        for (int mf = 0; mf < 4; ++mf) {
            int o = wm * 64 + mf * 16 + l15;
            afA[mf] = *(const short8*)((const char*)lds_w0 + o * 64 +
                                       ((lhi ^ ((o >> 1) & 3)) << 4));
        }

        #pragma unroll
        for (int tap = 0; tap < 27; ++tap) {
            int kd = tap / 9, r9 = tap - kd * 9;
            int kh = r9 / 3, kw = r9 - kh * 3;

            // bf(tap): x-tile is chunk-stable -> read BEFORE the barrier
            short8 xf[4];
            #pragma unroll
            for (int nf = 0; nf < 4; ++nf) {
                int n = wn * 64 + nf * 16;
                int zi = n >> 7, yi = (n >> 5) & 3;
                int h = ((zi + kd) * 6 + (yi + kh)) * 34 + (n & 31) + kw + l15;
                xf[nf] = *(const short8*)((const char*)lds_x + h * 64 +
                                          ((lhi ^ ((h >> 1) & 3)) << 4));
            }

            if (tap < 25)            // stage tap+2 into the free buffer
                gload16(wbc + (size_t)(tap + 2) * 4096 + wid * 512 + lane * 8,
                        (void*)((char*)wbuf[(tap + 2) % 3] + wid * 1024));

            if (tap < 26) {
                if (tap < 25) asm volatile("s_waitcnt vmcnt(1)" ::: "memory");
                else          asm volatile("s_waitcnt vmcnt(0)" ::: "memory");
                __builtin_amdgcn_s_barrier();
                asm volatile("" ::: "memory");
                // af(tap+1) -> alternate set
                const short* wnext = wbuf[(tap + 1) % 3];
                if ((tap & 1) == 0) {
                    #pragma unroll
                    for (int mf = 0; mf < 4; ++mf) {
                        int o = wm * 64 + mf * 16 + l15;
                        afB[mf] = *(const short8*)((const char*)wnext + o * 64 +
                                                   ((lhi ^ ((o >> 1) & 3)) << 4));
                    }
                } else {
                    #pragma unroll
                    for (int mf = 0; mf < 4; ++mf) {
                        int o = wm * 64 + mf * 16 + l15;
                        afA[mf] = *(const short8*)((const char*)wnext + o * 64 +
                                                   ((lhi ^ ((o >> 1) & 3)) << 4));
                    }
                }
            }

            __builtin_amdgcn_s_setprio(1);
            #pragma unroll
            for (int nf = 0; nf < 4; ++nf) {
                #pragma unroll
                for (int mf = 0; mf < 4; ++mf) {
                    acc[mf][nf] = __builtin_amdgcn_mfma_f32_16x16x32_bf16(
                        ((tap & 1) == 0) ? afA[mf] : afB[mf], xf[nf], acc[mf][nf], 0, 0, 0);
                }
            }
            __builtin_amdgcn_s_setprio(0);
        }
    }

    // epilogue: D layout col=lane&15 (spatial), row=(lane>>4)*4+j (c_out)
    float bv[4][4];
    #pragma unroll
    for (int mf = 0; mf < 4; ++mf)
        #pragma unroll
        for (int j = 0; j < 4; ++j)
            bv[mf][j] = bias[wm * 64 + mf * 16 + lhi * 4 + j];

    #pragma unroll
    for (int mf = 0; mf < 4; ++mf) {
        int o = wm * 64 + mf * 16 + lhi * 4;
        #pragma unroll
        for (int nf = 0; nf < 4; ++nf) {
            int n = wn * 64 + nf * 16;
            int zi = n >> 7, yi = (n >> 5) & 3, wcol = (n & 31) + l15;
            size_t obase = ((size_t)(b * CO + o)) * SP + (size_t)(z0 + zi) * 1024 + (y0 + yi) * 32 + wcol;
            #pragma unroll
            for (int j = 0; j < 4; ++j)
                out[obase + (size_t)j * SP] = acc[mf][nf][j] + bv[mf][j];
        }
    }
}

extern "C" void kernel_launch(void* const* d_in, const int* in_sizes, int n_in,
                              void* d_out, int out_size, void* d_ws, size_t ws_size,
                              hipStream_t stream) {
    const float* x  = (const float*)d_in[0];
    const float* s  = (const float*)d_in[1];
    const float* w  = (const float*)d_in[2];
    const float* bb = (const float*)d_in[3];
    const float* aw = (const float*)d_in[4];
    const float* ab = (const float*)d_in[5];
    float* out = (float*)d_out;

    // workspace layout
    float* style_m = (float*)d_ws;                                      // 4 KB
    short* wmodT   = (short*)((char*)d_ws + 4096);                      // 7,077,888 B
    short* xT      = (short*)((char*)d_ws + 4096 + 7077888);            // 67,108,864 B
    float* zpage   = (float*)((char*)d_ws + 4096 + 7077888 + 67108864); // 256 B zeros

    k_style<<<BATCH, 128, 0, stream>>>(s, aw, ab, style_m, zpage);
    k_wmod<<<BATCH * CO, 64, 0, stream>>>(w, style_m, wmodT);
    k_xt<<<BATCH * 4 * 128, 256, 0, stream>>>(x, xT);
    k_conv<<<BATCH * 128, 512, 0, stream>>>(xT, wmodT, bb, out, (const short*)zpage);
}

// Round 6
// 319.824 us; speedup vs baseline: 1.9674x; 1.5298x over previous
//
#include <hip/hip_runtime.h>
#include <stdint.h>
#include <stddef.h>

typedef __attribute__((ext_vector_type(8))) short short8;
typedef __attribute__((ext_vector_type(16))) float f32x16;

#define CI 128
#define CO 128
#define SP 32768          // 32*32*32
#define BATCH 8
#define STYLED 512
#define KV 3456           // CI*27

typedef __attribute__((address_space(1))) const void gvoid_t;
typedef __attribute__((address_space(3))) void lvoid_t;
__device__ __forceinline__ void gload16(const void* g, void* l) {
    __builtin_amdgcn_global_load_lds((gvoid_t*)g, (lvoid_t*)l, 16, 0, 0);
}

__device__ __forceinline__ short f2bf(float f) {
    uint32_t u = __builtin_bit_cast(uint32_t, f);
    u = (u + 0x7FFFu + ((u >> 16) & 1u)) >> 16;
    return (short)(u & 0xFFFFu);
}

// style_m[b][i] = 1 + affine_b[i] + sum_d s[b][d]*affine_w[i][d]; block 0 zeros zp
__global__ void k_style(const float* __restrict__ s, const float* __restrict__ aw,
                        const float* __restrict__ ab, float* __restrict__ m,
                        float* __restrict__ zp) {
    __shared__ float ssh[STYLED];
    int b = blockIdx.x;
    int i = threadIdx.x;  // 128 threads
    if (b == 0 && i < 64) zp[i] = 0.f;   // 256B zeropage
    for (int r = 0; r < STYLED / 128; ++r) ssh[r * 128 + i] = s[b * STYLED + r * 128 + i];
    __syncthreads();
    float acc = ab[i] + 1.0f;
    const float4* awr = (const float4*)(aw + (size_t)i * STYLED);
    for (int d4 = 0; d4 < STYLED / 4; ++d4) {
        float4 v = awr[d4];
        acc += v.x * ssh[d4 * 4] + v.y * ssh[d4 * 4 + 1] + v.z * ssh[d4 * 4 + 2] + v.w * ssh[d4 * 4 + 3];
    }
    m[b * CI + i] = acc;
}

// wmodT[b][kk][o][32ci] (kk = c32*27 + tap), granule g stored at g ^ ((o>>1)&3)
__global__ void k_wmod(const float* __restrict__ w, const float* __restrict__ m,
                       short* __restrict__ wt) {
    int b = blockIdx.x >> 7;
    int o = blockIdx.x & 127;
    int lane = threadIdx.x;   // 64 threads
    const float* wrow = w + (size_t)o * KV;
    const float* mrow = m + b * CI;
    float sum = 0.f;
    for (int e = lane; e < KV; e += 64) {
        int i = e / 27;
        float v = wrow[e] * mrow[i];
        sum += v * v;
    }
    #pragma unroll
    for (int off = 32; off >= 1; off >>= 1) sum += __shfl_xor(sum, off);
    float scale = 1.0f / sqrtf(sum + 1e-8f);
    int ophase = (o >> 1) & 3;
    for (int e = lane; e < KV; e += 64) {
        int i = e / 27;
        int k = e - i * 27;
        float v = wrow[e] * mrow[i] * scale;
        int kk = (i >> 5) * 27 + k;          // ci32 chunk * 27 + tap
        int il = i & 31, g = il >> 3, r = il & 7;
        int gl = g ^ ophase;
        wt[(((size_t)(b * 108 + kk)) * 128 + o) * 32 + gl * 8 + r] = f2bf(v);
    }
}

// xT[b][sp][ci] bf16 from x[b][ci][z][y][w] f32. Thread = 1 sp, 32 ch.
__global__ void k_xt(const float* __restrict__ x, short* __restrict__ xt) {
    int bid = blockIdx.x;              // 4096 = 8b * 4c * 128spb
    int b = bid >> 9, c = (bid >> 7) & 3, spb = bid & 127;
    int sp = spb * 256 + threadIdx.x;
    const float* src = x + ((size_t)(b * CI + c * 32)) * SP + sp;
    float f[32];
    #pragma unroll
    for (int ch = 0; ch < 32; ++ch) f[ch] = src[(size_t)ch * SP];
    short8 v[4];
    #pragma unroll
    for (int q = 0; q < 4; ++q)
        #pragma unroll
        for (int j = 0; j < 8; ++j) v[q][j] = f2bf(f[q * 8 + j]);
    short* dst = xt + (size_t)(b * SP + sp) * CI + c * 32;
    #pragma unroll
    for (int q = 0; q < 4; ++q) *(short8*)(dst + q * 8) = v[q];
}

// Implicit-GEMM conv. Block = 128co x 512sp (4z*4y*32w), 8 waves 2M x 4N,
// wave tile 64x128, mfma_f32_32x32x16. 3-tap phases, 9-buffer weight ring,
// counted vmcnt(3) with 2-phase stage-ahead; vmcnt(0) only at chunk boundary.
__launch_bounds__(512, 2)
__global__ void k_conv(const short* __restrict__ xt, const short* __restrict__ wt,
                       const float* __restrict__ bias, float* __restrict__ out,
                       const short* __restrict__ zp) {
    __shared__ short lds_x[77 * 512];    // 78,848 B: 1224 halo rows (6z*6y*34w) of 64B + pad
    __shared__ short lds_w[9 * 4096];    // 73,728 B: ring of 9 tap-buffers (128o x 32ci)

    int bid = blockIdx.x;
    int b = bid & 7;                 // sample -> XCD affinity
    int s = bid >> 3;                // 0..63
    int z0 = (s & 7) * 4, y0 = (s >> 3) * 4;
    int tid = threadIdx.x, lane = tid & 63, wid = tid >> 6;
    int wm = wid >> 2;               // 0..1 : co half (64 rows)
    int wn = wid & 3;                // 0..3 : z within tile
    int l31 = lane & 31, g5 = lane >> 5;

    const char* xb = (const char*)(xt + (size_t)b * SP * CI);
    const char* wb = (const char*)(wt + (size_t)b * 108 * 4096);

    // hoisted x-halo source offsets (bytes; -1 = zeropage)
    int xoff[10];
    #pragma unroll
    for (int j = 0; j < 10; ++j) {
        int ss = wid + 8 * j;
        int G = ss * 64 + lane;
        int row = G >> 2, pg = G & 3;
        int q = pg ^ ((row >> 1) & 3);       // source pre-swizzle
        int zh = row / 204, r2 = row - zh * 204;
        int yh = r2 / 34, wh = r2 - yh * 34;
        int zz = z0 + zh - 1, yy = y0 + yh - 1, ww = wh - 1;
        bool ok = (ss < 77) && (row < 1224) &&
                  ((unsigned)zz < 32u) && ((unsigned)yy < 32u) && ((unsigned)ww < 32u);
        xoff[j] = ok ? ((zz * 1024 + yy * 32 + ww) * 256 + q * 16) : -1;
    }

    f32x16 acc[2][4];
    #pragma unroll
    for (int mf = 0; mf < 2; ++mf)
        #pragma unroll
        for (int nf = 0; nf < 4; ++nf)
            #pragma unroll
            for (int e = 0; e < 16; ++e) acc[mf][nf][e] = 0.f;

    // prologue: stage weights kk=0..5 (covers phases 0,1 of chunk 0)
    #pragma unroll
    for (int q2 = 0; q2 < 6; ++q2)
        gload16(wb + (size_t)q2 * 8192 + wid * 1024 + lane * 16,
                (void*)((char*)lds_w + q2 * 8192 + wid * 1024));

    #pragma unroll 1
    for (int c = 0; c < 4; ++c) {
        // x-halo stage for this ci32 chunk (lds_x readers retired at prior barrier)
        #pragma unroll
        for (int j = 0; j < 10; ++j) {
            int ss = wid + 8 * j;
            if (ss < 77) {
                const char* src = (xoff[j] >= 0) ? (xb + xoff[j] + c * 64) : (const char*)zp;
                gload16(src, (void*)((char*)lds_x + ss * 1024));
            }
        }
        asm volatile("s_waitcnt vmcnt(0)" ::: "memory");   // chunk boundary: full drain
        __builtin_amdgcn_s_barrier();
        asm volatile("" ::: "memory");

        int kk0 = c * 27;
        #pragma unroll 1
        for (int ph = 0; ph < 9; ++ph) {
            // stage phase ph+2's 3 taps (wave wid stages its 1KB segment of each)
            #pragma unroll
            for (int q = 0; q < 3; ++q) {
                int kt = kk0 + ph * 3 + 6 + q;
                int buf = kt % 9;
                int ksrc = (kt >= 108) ? kt - 108 : kt;    // dummy wrap at tail
                gload16(wb + (size_t)ksrc * 8192 + wid * 1024 + lane * 16,
                        (void*)((char*)lds_w + buf * 8192 + wid * 1024));
            }
            // compute 3 taps (barrier-free: compiler pipelines reads with MFMA)
            #pragma unroll
            for (int t = 0; t < 3; ++t) {
                int tap = ph * 3 + t;
                int kd = tap / 9, r9 = tap - kd * 9;
                int kh = r9 / 3, kw = r9 - kh * 3;
                const char* wbuf = (const char*)lds_w + ((kk0 + tap) % 9) * 8192;
                int hb = (wn + kd) * 204 + kh * 34 + l31 + kw;

                #pragma unroll
                for (int ks = 0; ks < 2; ++ks) {
                    short8 af[2];
                    #pragma unroll
                    for (int mf = 0; mf < 2; ++mf) {
                        int o = wm * 64 + mf * 32 + l31;
                        int qq = (ks * 2 + g5) ^ ((o >> 1) & 3);
                        af[mf] = *(const short8*)(wbuf + o * 64 + qq * 16);
                    }
                    #pragma unroll
                    for (int nf = 0; nf < 4; ++nf) {
                        int h = hb + nf * 34;
                        int qq = (ks * 2 + g5) ^ ((h >> 1) & 3);
                        short8 bf = *(const short8*)((const char*)lds_x + h * 64 + qq * 16);
                        acc[0][nf] = __builtin_amdgcn_mfma_f32_32x32x16_bf16(af[0], bf, acc[0][nf], 0, 0, 0);
                        acc[1][nf] = __builtin_amdgcn_mfma_f32_32x32x16_bf16(af[1], bf, acc[1][nf], 0, 0, 0);
                    }
                }
            }
            asm volatile("s_waitcnt vmcnt(3)" ::: "memory");  // counted: next phase landed,
            __builtin_amdgcn_s_barrier();                     // staged-this-phase in flight
            asm volatile("" ::: "memory");
        }
    }

    // epilogue: D col=lane&31 (w), row=(j&3)+8*(j>>2)+4*(lane>>5) (co)  [R4-verified]
    size_t ob = (size_t)b * CO * SP;
    #pragma unroll
    for (int mf = 0; mf < 2; ++mf)
        #pragma unroll
        for (int nf = 0; nf < 4; ++nf) {
            int z = z0 + wn, y = y0 + nf;
            size_t base = ob + (size_t)z * 1024 + y * 32 + l31;
            #pragma unroll
            for (int j = 0; j < 16; ++j) {
                int co = wm * 64 + mf * 32 + (j & 3) + 8 * (j >> 2) + 4 * g5;
                out[base + (size_t)co * SP] = acc[mf][nf][j] + bias[co];
            }
        }
}

extern "C" void kernel_launch(void* const* d_in, const int* in_sizes, int n_in,
                              void* d_out, int out_size, void* d_ws, size_t ws_size,
                              hipStream_t stream) {
    const float* x  = (const float*)d_in[0];
    const float* s  = (const float*)d_in[1];
    const float* w  = (const float*)d_in[2];
    const float* bb = (const float*)d_in[3];
    const float* aw = (const float*)d_in[4];
    const float* ab = (const float*)d_in[5];
    float* out = (float*)d_out;

    // workspace layout
    float* style_m = (float*)d_ws;                                      // 4 KB
    short* wmodT   = (short*)((char*)d_ws + 4096);                      // 7,077,888 B
    short* xT      = (short*)((char*)d_ws + 4096 + 7077888);            // 67,108,864 B
    float* zpage   = (float*)((char*)d_ws + 4096 + 7077888 + 67108864); // 256 B zeros

    k_style<<<BATCH, 128, 0, stream>>>(s, aw, ab, style_m, zpage);
    k_wmod<<<BATCH * CO, 64, 0, stream>>>(w, style_m, wmodT);
    k_xt<<<BATCH * 4 * 128, 256, 0, stream>>>(x, xT);
    k_conv<<<BATCH * 64, 512, 0, stream>>>(xT, wmodT, bb, out, (const short*)zpage);
}

// Round 7
// 313.167 us; speedup vs baseline: 2.0092x; 1.0213x over previous
//
#include <hip/hip_runtime.h>
#include <stdint.h>
#include <stddef.h>

typedef __attribute__((ext_vector_type(8))) short short8;
typedef __attribute__((ext_vector_type(16))) float f32x16;

#define CI 128
#define CO 128
#define SP 32768          // 32*32*32
#define BATCH 8
#define STYLED 512
#define KV 3456           // CI*27

typedef __attribute__((address_space(1))) const void gvoid_t;
typedef __attribute__((address_space(3))) void lvoid_t;
__device__ __forceinline__ void gload16(const void* g, void* l) {
    __builtin_amdgcn_global_load_lds((gvoid_t*)g, (lvoid_t*)l, 16, 0, 0);
}

__device__ __forceinline__ short f2bf(float f) {
    uint32_t u = __builtin_bit_cast(uint32_t, f);
    u = (u + 0x7FFFu + ((u >> 16) & 1u)) >> 16;
    return (short)(u & 0xFFFFu);
}

// style_m[b][i] = 1 + affine_b[i] + sum_d s[b][d]*affine_w[i][d]; block 0 zeros zp
__global__ void k_style(const float* __restrict__ s, const float* __restrict__ aw,
                        const float* __restrict__ ab, float* __restrict__ m,
                        float* __restrict__ zp) {
    __shared__ float ssh[STYLED];
    int b = blockIdx.x;
    int i = threadIdx.x;  // 128 threads
    if (b == 0 && i < 64) zp[i] = 0.f;   // 256B zeropage
    for (int r = 0; r < STYLED / 128; ++r) ssh[r * 128 + i] = s[b * STYLED + r * 128 + i];
    __syncthreads();
    float acc = ab[i] + 1.0f;
    const float4* awr = (const float4*)(aw + (size_t)i * STYLED);
    for (int d4 = 0; d4 < STYLED / 4; ++d4) {
        float4 v = awr[d4];
        acc += v.x * ssh[d4 * 4] + v.y * ssh[d4 * 4 + 1] + v.z * ssh[d4 * 4 + 2] + v.w * ssh[d4 * 4 + 3];
    }
    m[b * CI + i] = acc;
}

// wmodT[b][kk][o][32ci] (kk = c32*27 + tap), granule g stored at g ^ ((o>>1)&3)
__global__ void k_wmod(const float* __restrict__ w, const float* __restrict__ m,
                       short* __restrict__ wt) {
    int b = blockIdx.x >> 7;
    int o = blockIdx.x & 127;
    int lane = threadIdx.x;   // 64 threads
    const float* wrow = w + (size_t)o * KV;
    const float* mrow = m + b * CI;
    float sum = 0.f;
    for (int e = lane; e < KV; e += 64) {
        int i = e / 27;
        float v = wrow[e] * mrow[i];
        sum += v * v;
    }
    #pragma unroll
    for (int off = 32; off >= 1; off >>= 1) sum += __shfl_xor(sum, off);
    float scale = 1.0f / sqrtf(sum + 1e-8f);
    int ophase = (o >> 1) & 3;
    for (int e = lane; e < KV; e += 64) {
        int i = e / 27;
        int k = e - i * 27;
        float v = wrow[e] * mrow[i] * scale;
        int kk = (i >> 5) * 27 + k;          // ci32 chunk * 27 + tap
        int il = i & 31, g = il >> 3, r = il & 7;
        int gl = g ^ ophase;
        wt[(((size_t)(b * 108 + kk)) * 128 + o) * 32 + gl * 8 + r] = f2bf(v);
    }
}

// xT[b][sp][ci] bf16 from x[b][ci][z][y][w] f32. Thread = 2 sp, 32 ch (float2 loads).
__global__ void k_xt(const float* __restrict__ x, short* __restrict__ xt) {
    int bid = blockIdx.x;              // 2048 = 8b * 4c * 64spb
    int b = bid >> 8, c = (bid >> 6) & 3, spb = bid & 63;
    int sp = spb * 512 + threadIdx.x * 2;
    const float* src = x + ((size_t)(b * CI + c * 32)) * SP + sp;
    float2 f[32];
    #pragma unroll
    for (int ch = 0; ch < 32; ++ch) f[ch] = *(const float2*)(src + (size_t)ch * SP);
    short8 v0[4], v1[4];
    #pragma unroll
    for (int q = 0; q < 4; ++q)
        #pragma unroll
        for (int j = 0; j < 8; ++j) {
            v0[q][j] = f2bf(f[q * 8 + j].x);
            v1[q][j] = f2bf(f[q * 8 + j].y);
        }
    short* d0 = xt + (size_t)(b * SP + sp) * CI + c * 32;
    #pragma unroll
    for (int q = 0; q < 4; ++q) *(short8*)(d0 + q * 8) = v0[q];
    #pragma unroll
    for (int q = 0; q < 4; ++q) *(short8*)(d0 + CI + q * 8) = v1[q];
}

// Implicit-GEMM conv. Block = 4 waves (256 thr), block tile 128co x 512sp
// (4z*4y*32w). Wave tile 128x128 (wave grid 1x4 over sp) -> 0.5KB LDS per
// MFMA: LDS supply ~= MFMA demand (balanced). mfma_f32_32x32x16, acc 256 VGPR,
// 1 wave/SIMD. Weights: ring-4 LDS bufs staged 2 taps ahead via gload_lds,
// barrier every 2 taps. x-halo single-buffered, restaged per ci32 chunk.
__launch_bounds__(256, 1)
__global__ void k_conv(const short* __restrict__ xt, const short* __restrict__ wt,
                       const float* __restrict__ bias, float* __restrict__ out,
                       const short* __restrict__ zp) {
    __shared__ short lds_x[1232 * 32];    // 78,848 B: 1224 halo rows (6z*6y*34w) of 64B + pad
    __shared__ short lds_w[4][128 * 32];  // ring of 4 tap-buffers, 8KB each

    int bid = blockIdx.x;
    int b = bid & 7;                 // sample -> XCD affinity
    int s = bid >> 3;                // 0..63
    int z0 = (s & 7) * 4, y0 = (s >> 3) * 4;
    int tid = threadIdx.x, lane = tid & 63, wid = tid >> 6;   // 4 waves
    int l31 = lane & 31, g5 = lane >> 5;

    const char* xb = (const char*)(xt + (size_t)b * SP * CI);
    const char* wb = (const char*)(wt + (size_t)b * 108 * 4096);

    // hoisted x-halo source byte offsets (-1 = zeropage); slot s2 = wid + 4j
    int xoff[20];
    #pragma unroll
    for (int j = 0; j < 20; ++j) {
        int s2 = wid + 4 * j;
        int G = s2 * 64 + lane;
        int row = G >> 2, pg = G & 3;
        int q = pg ^ ((row >> 1) & 3);       // source pre-swizzle
        int zh = row / 204, r2 = row - zh * 204;
        int yh = r2 / 34, wh = r2 - yh * 34;
        int zz = z0 + zh - 1, yy = y0 + yh - 1, ww = wh - 1;
        bool ok = (row < 1224) &&
                  ((unsigned)zz < 32u) && ((unsigned)yy < 32u) && ((unsigned)ww < 32u);
        xoff[j] = ok ? ((zz * 1024 + yy * 32 + ww) * 256 + q * 16) : -1;
    }

    f32x16 acc[4][4];
    #pragma unroll
    for (int mf = 0; mf < 4; ++mf)
        #pragma unroll
        for (int nf = 0; nf < 4; ++nf)
            #pragma unroll
            for (int e = 0; e < 16; ++e) acc[mf][nf][e] = 0.f;

    #pragma unroll 1
    for (int c = 0; c < 4; ++c) {
        // ---- stage x halo (single buffer; prior readers retired at last barrier)
        #pragma unroll
        for (int j = 0; j < 20; ++j) {
            int s2 = wid + 4 * j;
            if (s2 * 64 < 4896) {
                const char* src = (xoff[j] >= 0) ? (xb + xoff[j] + c * 64) : (const char*)zp;
                gload16(src, (void*)((char*)lds_x + s2 * 1024));
            }
        }
        int kk0 = c * 27;
        // ---- stage taps 0,1 into bufs 0,1 (per wave: 2KB segment each)
        #pragma unroll
        for (int t = 0; t < 2; ++t)
            #pragma unroll
            for (int iss = 0; iss < 2; ++iss)
                gload16(wb + (size_t)(kk0 + t) * 8192 + wid * 2048 + iss * 1024 + lane * 16,
                        (void*)((char*)lds_w[t] + wid * 2048 + iss * 1024));
        asm volatile("s_waitcnt vmcnt(0)" ::: "memory");
        __builtin_amdgcn_s_barrier();
        asm volatile("" ::: "memory");

        #pragma unroll 1
        for (int ph = 0; ph < 13; ++ph) {
            int t0 = 2 * ph;
            // stage taps t0+2, t0+3 (ring: bufs retired at the last barrier)
            #pragma unroll
            for (int dt = 2; dt < 4; ++dt) {
                int t = t0 + dt;
                if (t < 27) {
                    #pragma unroll
                    for (int iss = 0; iss < 2; ++iss)
                        gload16(wb + (size_t)(kk0 + t) * 8192 + wid * 2048 + iss * 1024 + lane * 16,
                                (void*)((char*)lds_w[t & 3] + wid * 2048 + iss * 1024));
                }
            }
            // compute taps t0, t0+1
            #pragma unroll
            for (int dt = 0; dt < 2; ++dt) {
                int tap = t0 + dt;
                int kd = tap / 9, r9 = tap - kd * 9;
                int kh = r9 / 3, kw = r9 - kh * 3;
                const char* wbuf = (const char*)lds_w[tap & 3];
                int hb = (wid + kd) * 204 + kh * 34 + l31 + kw;
                #pragma unroll
                for (int ks = 0; ks < 2; ++ks) {
                    int qsel = ks * 2 + g5;
                    short8 af[4], bf[4];
                    #pragma unroll
                    for (int mf = 0; mf < 4; ++mf) {
                        int qq = qsel ^ ((l31 >> 1) & 3);
                        af[mf] = *(const short8*)(wbuf + (mf * 32 + l31) * 64 + qq * 16);
                    }
                    #pragma unroll
                    for (int nf = 0; nf < 4; ++nf) {
                        int h = hb + nf * 34;
                        int qq = qsel ^ ((h >> 1) & 3);
                        bf[nf] = *(const short8*)((const char*)lds_x + h * 64 + qq * 16);
                    }
                    #pragma unroll
                    for (int nf = 0; nf < 4; ++nf)
                        #pragma unroll
                        for (int mf = 0; mf < 4; ++mf)
                            acc[mf][nf] = __builtin_amdgcn_mfma_f32_32x32x16_bf16(
                                af[mf], bf[nf], acc[mf][nf], 0, 0, 0);
                }
            }
            asm volatile("s_waitcnt vmcnt(0)" ::: "memory");
            __builtin_amdgcn_s_barrier();
            asm volatile("" ::: "memory");
        }
        // tap 26 (staged in ph=12; buf 2)
        {
            const int tap = 26;                 // kd=2, kh=2, kw=2
            const char* wbuf = (const char*)lds_w[tap & 3];
            int hb = (wid + 2) * 204 + 2 * 34 + l31 + 2;
            #pragma unroll
            for (int ks = 0; ks < 2; ++ks) {
                int qsel = ks * 2 + g5;
                short8 af[4], bf[4];
                #pragma unroll
                for (int mf = 0; mf < 4; ++mf) {
                    int qq = qsel ^ ((l31 >> 1) & 3);
                    af[mf] = *(const short8*)(wbuf + (mf * 32 + l31) * 64 + qq * 16);
                }
                #pragma unroll
                for (int nf = 0; nf < 4; ++nf) {
                    int h = hb + nf * 34;
                    int qq = qsel ^ ((h >> 1) & 3);
                    bf[nf] = *(const short8*)((const char*)lds_x + h * 64 + qq * 16);
                }
                #pragma unroll
                for (int nf = 0; nf < 4; ++nf)
                    #pragma unroll
                    for (int mf = 0; mf < 4; ++mf)
                        acc[mf][nf] = __builtin_amdgcn_mfma_f32_32x32x16_bf16(
                            af[mf], bf[nf], acc[mf][nf], 0, 0, 0);
            }
        }
        __builtin_amdgcn_s_barrier();        // retire x reads before next chunk restage
        asm volatile("" ::: "memory");
    }

    // epilogue: D col=lane&31 (w), row=(j&3)+8*(j>>2)+4*(lane>>5) (co)  [R4/R6-verified]
    size_t ob = (size_t)b * CO * SP;
    #pragma unroll
    for (int mf = 0; mf < 4; ++mf) {
        float bv[16];
        #pragma unroll
        for (int j = 0; j < 16; ++j)
            bv[j] = bias[mf * 32 + (j & 3) + 8 * (j >> 2) + 4 * g5];
        #pragma unroll
        for (int nf = 0; nf < 4; ++nf) {
            size_t base = ob + (size_t)(z0 + wid) * 1024 + (y0 + nf) * 32 + l31;
            #pragma unroll
            for (int j = 0; j < 16; ++j) {
                int co = mf * 32 + (j & 3) + 8 * (j >> 2) + 4 * g5;
                out[base + (size_t)co * SP] = acc[mf][nf][j] + bv[j];
            }
        }
    }
}

extern "C" void kernel_launch(void* const* d_in, const int* in_sizes, int n_in,
                              void* d_out, int out_size, void* d_ws, size_t ws_size,
                              hipStream_t stream) {
    const float* x  = (const float*)d_in[0];
    const float* s  = (const float*)d_in[1];
    const float* w  = (const float*)d_in[2];
    const float* bb = (const float*)d_in[3];
    const float* aw = (const float*)d_in[4];
    const float* ab = (const float*)d_in[5];
    float* out = (float*)d_out;

    // workspace layout
    float* style_m = (float*)d_ws;                                      // 4 KB
    short* wmodT   = (short*)((char*)d_ws + 4096);                      // 7,077,888 B
    short* xT      = (short*)((char*)d_ws + 4096 + 7077888);            // 67,108,864 B
    float* zpage   = (float*)((char*)d_ws + 4096 + 7077888 + 67108864); // 256 B zeros

    k_style<<<BATCH, 128, 0, stream>>>(s, aw, ab, style_m, zpage);
    k_wmod<<<BATCH * CO, 64, 0, stream>>>(w, style_m, wmodT);
    k_xt<<<BATCH * 4 * 64, 256, 0, stream>>>(x, xT);
    k_conv<<<BATCH * 64, 256, 0, stream>>>(xT, wmodT, bb, out, (const float*)zpage ? (const short*)zpage : nullptr);
}